// Round 3
// baseline (220.078 us; speedup 1.0000x reference)
//
#include <hip/hip_runtime.h>
#include <stdint.h>

#define NB 256
#define NL 128
#define ND1 512
#define ND2 512

#define BI 256              // i-tile width per block (n-dim of GEMM)
#define BK 64               // k-tile depth (j-dim)
#define NKT (ND2 / BK)      // 8 k-tiles
#define LDST 72             // LDS row stride (bf16 elems): 144 B rows, 16B-aligned, bank phase +4/row

typedef float float4_t __attribute__((ext_vector_type(4)));
typedef __bf16 bf16x8_t __attribute__((ext_vector_type(8)));
typedef unsigned short ushort4_t __attribute__((ext_vector_type(4)));
typedef unsigned short ushort8_t __attribute__((ext_vector_type(8)));

// fp32 -> bf16 round-to-nearest-even
__device__ __forceinline__ unsigned short f2bf(float f) {
    unsigned int u = __float_as_uint(f);
    u += 0x7FFFu + ((u >> 16) & 1u);
    return (unsigned short)(u >> 16);
}

__device__ __forceinline__ ushort4_t cvt4(float4_t v) {
    ushort4_t u;
    u.x = f2bf(v.x); u.y = f2bf(v.y); u.z = f2bf(v.z); u.w = f2bf(v.w);
    return u;
}

// Z = T2 (128 x 512, k=j) x W^T (512 x 512; B[n=i][k=j], rows k-contiguous!)
// out[b,l] = sum_i Z[l,i] * t1[b,l,i]
//
// 512-thread blocks, BI=256: grid = 256 b x 2 it = 512 blocks = EXACTLY
// 2 blocks/CU x 256 CU co-resident (single round, no tail).
// 8 waves = 4(l-rows) x 2(i-halves); each wave computes a 32x128 sub-tile
// (2x8 16x16 fragments, 64 AGPR acc — unchanged fragment layout).
// Pipelined k-loop: register-prefetch tile k+1 (12 float4 = 48 VGPR)
// during compute of tile k; raw s_barrier so loads stay in flight.
// lb(512,4) pins regs <=128 -> 4 waves/SIMD.
__global__ __launch_bounds__(512, 4) void pdot_kernel(
    const float* __restrict__ t1, const float* __restrict__ t2,
    const int* __restrict__ pidx, const float* __restrict__ wgt,
    float* __restrict__ out)
{
    __shared__ unsigned short sA[NL * LDST];   // T2 tile bf16: [128 l][64 j + pad]
    __shared__ unsigned short sB[BI * LDST];   // W  tile bf16: [256 i][64 j + pad]

    const int g  = blockIdx.x;
    const int b  = g & (NB - 1);   // batch in low bits: both i-tiles of b share g%8 (XCD) -> t2 L2 reuse
    const int it = g >> 8;
    const int i0 = it * BI;

    const int t  = threadIdx.x;
    const int w  = t >> 6;         // wave 0..7
    const int wv = w & 3;          // l-group: rows wv*32..wv*32+31
    const int ih = w >> 2;         // i-half: cols ih*128..ih*128+127
    const int ln = t & 63;
    const int nh = ln & 15;
    const int qd = ln >> 4;

    const int e = pidx[b];
    const float* aPtr  = t2  + (size_t)b * (NL * ND2);            // A source (l-major, j contig)
    const float* bPtr  = wgt + (size_t)e * (ND1 * ND2) + (size_t)i0 * ND2;  // B source (i-major, j contig)
    const float* t1p   = t1  + (size_t)b * (NL * ND1) + i0 + ih * 128;      // epilogue dot operand

    float4_t acc[2][8];
    #pragma unroll
    for (int i = 0; i < 2; ++i)
        #pragma unroll
        for (int j = 0; j < 8; ++j) {
            float4_t z = {0.f, 0.f, 0.f, 0.f};
            acc[i][j] = z;
        }

    // staging map: 512 threads, 16 float4-chunks per 64-col row -> 32 rows
    // per pass. A (128 rows): 4 passes. B (256 rows): 8 passes.
    const int s_row = t >> 4;          // 0..31, +p*32
    const int s_kq  = (t & 15) * 4;
    const size_t sOff = (size_t)s_row * ND2 + s_kq;

    float4_t pa[4], pb[8];   // in-flight prefetch registers (48 VGPRs)

    // ---- prologue: load+stage tile 0, issue prefetch of tile 1 ----
    #pragma unroll
    for (int p = 0; p < 4; ++p)
        pa[p] = *(const float4_t*)(aPtr + sOff + (size_t)p * (32 * ND2));
    #pragma unroll
    for (int p = 0; p < 8; ++p)
        pb[p] = *(const float4_t*)(bPtr + sOff + (size_t)p * (32 * ND2));
    #pragma unroll
    for (int p = 0; p < 4; ++p) {
        const int row = p * 32 + s_row;
        *(ushort4_t*)(&sA[row * LDST + s_kq]) = cvt4(pa[p]);
    }
    #pragma unroll
    for (int p = 0; p < 8; ++p) {
        const int row = p * 32 + s_row;
        *(ushort4_t*)(&sB[row * LDST + s_kq]) = cvt4(pb[p]);
    }
    #pragma unroll
    for (int p = 0; p < 4; ++p)
        pa[p] = *(const float4_t*)(aPtr + sOff + BK + (size_t)p * (32 * ND2));
    #pragma unroll
    for (int p = 0; p < 8; ++p)
        pb[p] = *(const float4_t*)(bPtr + sOff + BK + (size_t)p * (32 * ND2));
    __builtin_amdgcn_sched_barrier(0);
    asm volatile("s_waitcnt lgkmcnt(0)" ::: "memory");  // LDS writes of tile 0 published
    __builtin_amdgcn_sched_barrier(0);
    __builtin_amdgcn_s_barrier();              // raw barrier: prefetch loads stay in flight
    __builtin_amdgcn_sched_barrier(0);

    for (int kt = 0; kt < NKT; ++kt) {
        // ---- compute tile kt from LDS (prefetch for kt+1 flying) ----
        #pragma unroll
        for (int ks = 0; ks < 2; ++ks) {
            const int kf = ks * 32 + qd * 8;
            const int ra = wv * 32 + nh;
            bf16x8_t af0 = __builtin_bit_cast(bf16x8_t, *(ushort8_t*)(&sA[(ra     ) * LDST + kf]));
            bf16x8_t af1 = __builtin_bit_cast(bf16x8_t, *(ushort8_t*)(&sA[(ra + 16) * LDST + kf]));
            #pragma unroll
            for (int ns = 0; ns < 8; ++ns) {
                bf16x8_t bv = __builtin_bit_cast(bf16x8_t, *(ushort8_t*)(&sB[(ih * 128 + ns * 16 + nh) * LDST + kf]));
                acc[0][ns] = __builtin_amdgcn_mfma_f32_16x16x32_bf16(af0, bv, acc[0][ns], 0, 0, 0);
                acc[1][ns] = __builtin_amdgcn_mfma_f32_16x16x32_bf16(af1, bv, acc[1][ns], 0, 0, 0);
            }
        }

        if (kt < NKT - 1) {
            __builtin_amdgcn_sched_barrier(0);
            __builtin_amdgcn_s_barrier();      // all waves done READING tile kt
            __builtin_amdgcn_sched_barrier(0);

            // write tile kt+1 (compiler inserts counted vmcnt waits on pa/pb)
            #pragma unroll
            for (int p = 0; p < 4; ++p) {
                const int row = p * 32 + s_row;
                *(ushort4_t*)(&sA[row * LDST + s_kq]) = cvt4(pa[p]);
            }
            #pragma unroll
            for (int p = 0; p < 8; ++p) {
                const int row = p * 32 + s_row;
                *(ushort4_t*)(&sB[row * LDST + s_kq]) = cvt4(pb[p]);
            }
            // issue loads for tile kt+2 — these fly across the next barrier
            if (kt < NKT - 2) {
                const size_t k0 = (size_t)(kt + 2) * BK;
                #pragma unroll
                for (int p = 0; p < 4; ++p)
                    pa[p] = *(const float4_t*)(aPtr + sOff + k0 + (size_t)p * (32 * ND2));
                #pragma unroll
                for (int p = 0; p < 8; ++p)
                    pb[p] = *(const float4_t*)(bPtr + sOff + k0 + (size_t)p * (32 * ND2));
            }
            __builtin_amdgcn_sched_barrier(0);
            asm volatile("s_waitcnt lgkmcnt(0)" ::: "memory");  // tile kt+1 writes published
            __builtin_amdgcn_sched_barrier(0);
            __builtin_amdgcn_s_barrier();
            __builtin_amdgcn_sched_barrier(0);
        }
    }

    // epilogue: out[b,l] += sum over this wave's i-columns of Z[l,i]*t1[l,i]
    // C/D: col(n=i) = ih*128 + ns*16 + nh, row(m=l) = wv*32 + ms*16 + qd*4 + r
    #pragma unroll
    for (int ms = 0; ms < 2; ++ms) {
        #pragma unroll
        for (int r = 0; r < 4; ++r) {
            const int row = wv * 32 + ms * 16 + qd * 4 + r;
            float ps = 0.f;
            #pragma unroll
            for (int ns = 0; ns < 8; ++ns) {
                const float tv = t1p[(size_t)row * ND1 + ns * 16 + nh];
                ps += acc[ms][ns][r] * tv;
            }
            ps += __shfl_xor(ps, 1);
            ps += __shfl_xor(ps, 2);
            ps += __shfl_xor(ps, 4);
            ps += __shfl_xor(ps, 8);
            if (nh == 0) atomicAdd(&out[b * NL + row], ps);
        }
    }
}

extern "C" void kernel_launch(void* const* d_in, const int* in_sizes, int n_in,
                              void* d_out, int out_size, void* d_ws, size_t ws_size,
                              hipStream_t stream)
{
    const float* t1  = (const float*)d_in[0];
    const float* t2  = (const float*)d_in[1];
    const int* pidx  = (const int*)d_in[2];
    const float* wgt = (const float*)d_in[3];
    float* out = (float*)d_out;

    hipMemsetAsync(out, 0, (size_t)out_size * sizeof(float), stream);
    pdot_kernel<<<dim3(NB * (ND1 / BI)), dim3(512), 0, stream>>>(t1, t2, pidx, wgt, out);
}

// Round 4
// 218.267 us; speedup vs baseline: 1.0083x; 1.0083x over previous
//
#include <hip/hip_runtime.h>
#include <stdint.h>

#define NB 256
#define NL 128
#define ND1 512
#define ND2 512
#define NE 64

#define BI 256              // i-tile width per block (n-dim of GEMM)
#define BK 64               // k-tile depth (j-dim)
#define NKT (ND2 / BK)      // 8 k-tiles
#define LDST 72             // LDS row stride (bf16 elems): 144 B rows, 16B-aligned, bank phase +4/row

typedef float float4_t __attribute__((ext_vector_type(4)));
typedef __bf16 bf16x8_t __attribute__((ext_vector_type(8)));
typedef unsigned short ushort4_t __attribute__((ext_vector_type(4)));
typedef unsigned short ushort8_t __attribute__((ext_vector_type(8)));

// fp32 -> bf16 round-to-nearest-even
__device__ __forceinline__ unsigned short f2bf(float f) {
    unsigned int u = __float_as_uint(f);
    u += 0x7FFFu + ((u >> 16) & 1u);
    return (unsigned short)(u >> 16);
}

__device__ __forceinline__ ushort4_t cvt4(float4_t v) {
    ushort4_t u;
    u.x = f2bf(v.x); u.y = f2bf(v.y); u.z = f2bf(v.z); u.w = f2bf(v.w);
    return u;
}

// Pre-pass: counting-sort batches by expert id -> perm[0..NB).
// perm[k] = batch; batches sharing an expert are contiguous in perm.
// Rank order within a bin (LDS atomic order) is irrelevant: any permutation
// that clusters equal experts is equally correct/effective.
__global__ void sort_kernel(const int* __restrict__ pidx, int* __restrict__ perm)
{
    __shared__ int cnt[NE];
    __shared__ int base[NE];
    const int t = threadIdx.x;          // 256 threads
    if (t < NE) cnt[t] = 0;
    __syncthreads();
    const int e = pidx[t];
    const int r = atomicAdd(&cnt[e], 1);
    __syncthreads();
    if (t == 0) {
        int s = 0;
        for (int i = 0; i < NE; ++i) { base[i] = s; s += cnt[i]; }
    }
    __syncthreads();
    perm[base[e] + r] = t;
}

// Z = T2 (128 x 512, k=j) x W^T (512 x 512; B[n=i][k=j], rows k-contiguous!)
// out[b,l] = sum_i Z[l,i] * t1[b,l,i]
//
// 512-thread blocks, BI=256: grid = 512 blocks = 2 blocks/CU x 256 CU,
// single co-resident round. 8 waves = 4(l) x 2(i-half); per-wave 2x8
// 16x16 fragments (64 AGPR acc). Pipelined k-loop (register prefetch,
// raw s_barrier so loads fly across barriers).
//
// Expert-clustered placement: XCD x runs perm[x*32..x*32+31] (sorted by
// expert), so each expert's weight matrix is L2-filled ~once chip-wide
// instead of once per XCD it randomly lands on. it=0/1 of each b stay on
// the same XCD (t2 L2 reuse preserved).
template <bool USE_PERM>
__global__ __launch_bounds__(512, 4) void pdot_kernel(
    const float* __restrict__ t1, const float* __restrict__ t2,
    const int* __restrict__ pidx, const float* __restrict__ wgt,
    const int* __restrict__ perm, float* __restrict__ out)
{
    __shared__ unsigned short sA[NL * LDST];   // T2 tile bf16: [128 l][64 j + pad]
    __shared__ unsigned short sB[BI * LDST];   // W  tile bf16: [256 i][64 j + pad]

    const int g  = blockIdx.x;
    // slot: bijective remap of (g&255) so XCD (g&7) owns a contiguous
    // 32-entry slice of the expert-sorted batch list.
    const int slot = (g & 7) * 32 + ((g >> 3) & 31);
    const int b  = USE_PERM ? perm[slot] : (g & (NB - 1));
    const int it = g >> 8;
    const int i0 = it * BI;

    const int t  = threadIdx.x;
    const int w  = t >> 6;         // wave 0..7
    const int wv = w & 3;          // l-group: rows wv*32..wv*32+31
    const int ih = w >> 2;         // i-half: cols ih*128..ih*128+127
    const int ln = t & 63;
    const int nh = ln & 15;
    const int qd = ln >> 4;

    const int e = pidx[b];
    const float* aPtr  = t2  + (size_t)b * (NL * ND2);            // A source (l-major, j contig)
    const float* bPtr  = wgt + (size_t)e * (ND1 * ND2) + (size_t)i0 * ND2;  // B source (i-major, j contig)
    const float* t1p   = t1  + (size_t)b * (NL * ND1) + i0 + ih * 128;      // epilogue dot operand

    float4_t acc[2][8];
    #pragma unroll
    for (int i = 0; i < 2; ++i)
        #pragma unroll
        for (int j = 0; j < 8; ++j) {
            float4_t z = {0.f, 0.f, 0.f, 0.f};
            acc[i][j] = z;
        }

    // staging map: 512 threads, 16 float4-chunks per 64-col row -> 32 rows
    // per pass. A (128 rows): 4 passes. B (256 rows): 8 passes.
    const int s_row = t >> 4;          // 0..31, +p*32
    const int s_kq  = (t & 15) * 4;
    const size_t sOff = (size_t)s_row * ND2 + s_kq;

    float4_t pa[4], pb[8];   // in-flight prefetch registers (48 VGPRs)

    // ---- prologue: load+stage tile 0, issue prefetch of tile 1 ----
    #pragma unroll
    for (int p = 0; p < 4; ++p)
        pa[p] = *(const float4_t*)(aPtr + sOff + (size_t)p * (32 * ND2));
    #pragma unroll
    for (int p = 0; p < 8; ++p)
        pb[p] = *(const float4_t*)(bPtr + sOff + (size_t)p * (32 * ND2));
    #pragma unroll
    for (int p = 0; p < 4; ++p) {
        const int row = p * 32 + s_row;
        *(ushort4_t*)(&sA[row * LDST + s_kq]) = cvt4(pa[p]);
    }
    #pragma unroll
    for (int p = 0; p < 8; ++p) {
        const int row = p * 32 + s_row;
        *(ushort4_t*)(&sB[row * LDST + s_kq]) = cvt4(pb[p]);
    }
    #pragma unroll
    for (int p = 0; p < 4; ++p)
        pa[p] = *(const float4_t*)(aPtr + sOff + BK + (size_t)p * (32 * ND2));
    #pragma unroll
    for (int p = 0; p < 8; ++p)
        pb[p] = *(const float4_t*)(bPtr + sOff + BK + (size_t)p * (32 * ND2));
    __builtin_amdgcn_sched_barrier(0);
    asm volatile("s_waitcnt lgkmcnt(0)" ::: "memory");  // LDS writes of tile 0 published
    __builtin_amdgcn_sched_barrier(0);
    __builtin_amdgcn_s_barrier();              // raw barrier: prefetch loads stay in flight
    __builtin_amdgcn_sched_barrier(0);

    for (int kt = 0; kt < NKT; ++kt) {
        // ---- compute tile kt from LDS (prefetch for kt+1 flying) ----
        #pragma unroll
        for (int ks = 0; ks < 2; ++ks) {
            const int kf = ks * 32 + qd * 8;
            const int ra = wv * 32 + nh;
            bf16x8_t af0 = __builtin_bit_cast(bf16x8_t, *(ushort8_t*)(&sA[(ra     ) * LDST + kf]));
            bf16x8_t af1 = __builtin_bit_cast(bf16x8_t, *(ushort8_t*)(&sA[(ra + 16) * LDST + kf]));
            #pragma unroll
            for (int ns = 0; ns < 8; ++ns) {
                bf16x8_t bv = __builtin_bit_cast(bf16x8_t, *(ushort8_t*)(&sB[(ih * 128 + ns * 16 + nh) * LDST + kf]));
                acc[0][ns] = __builtin_amdgcn_mfma_f32_16x16x32_bf16(af0, bv, acc[0][ns], 0, 0, 0);
                acc[1][ns] = __builtin_amdgcn_mfma_f32_16x16x32_bf16(af1, bv, acc[1][ns], 0, 0, 0);
            }
        }

        if (kt < NKT - 1) {
            __builtin_amdgcn_sched_barrier(0);
            __builtin_amdgcn_s_barrier();      // all waves done READING tile kt
            __builtin_amdgcn_sched_barrier(0);

            // write tile kt+1 (compiler inserts counted vmcnt waits on pa/pb)
            #pragma unroll
            for (int p = 0; p < 4; ++p) {
                const int row = p * 32 + s_row;
                *(ushort4_t*)(&sA[row * LDST + s_kq]) = cvt4(pa[p]);
            }
            #pragma unroll
            for (int p = 0; p < 8; ++p) {
                const int row = p * 32 + s_row;
                *(ushort4_t*)(&sB[row * LDST + s_kq]) = cvt4(pb[p]);
            }
            // issue loads for tile kt+2 — these fly across the next barrier
            if (kt < NKT - 2) {
                const size_t k0 = (size_t)(kt + 2) * BK;
                #pragma unroll
                for (int p = 0; p < 4; ++p)
                    pa[p] = *(const float4_t*)(aPtr + sOff + k0 + (size_t)p * (32 * ND2));
                #pragma unroll
                for (int p = 0; p < 8; ++p)
                    pb[p] = *(const float4_t*)(bPtr + sOff + k0 + (size_t)p * (32 * ND2));
            }
            __builtin_amdgcn_sched_barrier(0);
            asm volatile("s_waitcnt lgkmcnt(0)" ::: "memory");  // tile kt+1 writes published
            __builtin_amdgcn_sched_barrier(0);
            __builtin_amdgcn_s_barrier();
            __builtin_amdgcn_sched_barrier(0);
        }
    }

    // epilogue: out[b,l] += sum over this wave's i-columns of Z[l,i]*t1[l,i]
    // C/D: col(n=i) = ih*128 + ns*16 + nh, row(m=l) = wv*32 + ms*16 + qd*4 + r
    #pragma unroll
    for (int ms = 0; ms < 2; ++ms) {
        #pragma unroll
        for (int r = 0; r < 4; ++r) {
            const int row = wv * 32 + ms * 16 + qd * 4 + r;
            float ps = 0.f;
            #pragma unroll
            for (int ns = 0; ns < 8; ++ns) {
                const float tv = t1p[(size_t)row * ND1 + ns * 16 + nh];
                ps += acc[ms][ns][r] * tv;
            }
            ps += __shfl_xor(ps, 1);
            ps += __shfl_xor(ps, 2);
            ps += __shfl_xor(ps, 4);
            ps += __shfl_xor(ps, 8);
            if (nh == 0) atomicAdd(&out[b * NL + row], ps);
        }
    }
}

extern "C" void kernel_launch(void* const* d_in, const int* in_sizes, int n_in,
                              void* d_out, int out_size, void* d_ws, size_t ws_size,
                              hipStream_t stream)
{
    const float* t1  = (const float*)d_in[0];
    const float* t2  = (const float*)d_in[1];
    const int* pidx  = (const int*)d_in[2];
    const float* wgt = (const float*)d_in[3];
    float* out = (float*)d_out;

    hipMemsetAsync(out, 0, (size_t)out_size * sizeof(float), stream);

    if (ws_size >= NB * sizeof(int)) {
        int* perm = (int*)d_ws;
        sort_kernel<<<dim3(1), dim3(NB), 0, stream>>>(pidx, perm);
        pdot_kernel<true><<<dim3(NB * (ND1 / BI)), dim3(512), 0, stream>>>(t1, t2, pidx, wgt, perm, out);
    } else {
        pdot_kernel<false><<<dim3(NB * (ND1 / BI)), dim3(512), 0, stream>>>(t1, t2, pidx, wgt, nullptr, out);
    }
}

// Round 5
// 207.587 us; speedup vs baseline: 1.0602x; 1.0514x over previous
//
#include <hip/hip_runtime.h>
#include <stdint.h>

#define NB 256
#define NL 128
#define ND1 512
#define ND2 512
#define NE 64

#define BI 128              // i-tile width per block
#define BK 64               // k-tile depth (j-dim)
#define NKT (ND2 / BK)      // 8 k-tiles
#define LDST 72             // LDS row stride (bf16 elems): 144 B rows, 16B-aligned, bank phase +4/row
#define BUFSZ ((NL + BI) * LDST)   // one dbuf buffer: sA then sB

typedef float float4_t __attribute__((ext_vector_type(4)));
typedef __bf16 bf16x8_t __attribute__((ext_vector_type(8)));
typedef unsigned short ushort4_t __attribute__((ext_vector_type(4)));
typedef unsigned short ushort8_t __attribute__((ext_vector_type(8)));

// fp32 -> bf16 round-to-nearest-even
__device__ __forceinline__ unsigned short f2bf(float f) {
    unsigned int u = __float_as_uint(f);
    u += 0x7FFFu + ((u >> 16) & 1u);
    return (unsigned short)(u >> 16);
}

__device__ __forceinline__ ushort4_t cvt4(float4_t v) {
    ushort4_t u;
    u.x = f2bf(v.x); u.y = f2bf(v.y); u.z = f2bf(v.z); u.w = f2bf(v.w);
    return u;
}

// Pre-pass: zero the output (replaces hipMemsetAsync launch) and, in block 0,
// counting-sort batches by expert id -> perm (expert-clustered XCD placement).
__global__ void pre_kernel(const int* __restrict__ pidx, int* __restrict__ perm,
                           float* __restrict__ out, int zero_n, int do_sort)
{
    const int g = blockIdx.x, t = threadIdx.x;
    const int idx = g * 256 + t;
    if (idx < zero_n) out[idx] = 0.f;
    if (do_sort && g == 0) {
        __shared__ int cnt[NE];
        __shared__ int base[NE];
        if (t < NE) cnt[t] = 0;
        __syncthreads();
        const int e = pidx[t];                 // t in [0,256) = NB
        const int r = atomicAdd(&cnt[e], 1);
        __syncthreads();
        if (t == 0) {
            int s = 0;
            for (int i = 0; i < NE; ++i) { base[i] = s; s += cnt[i]; }
        }
        __syncthreads();
        perm[base[e] + r] = t;
    }
}

// Z = T2 (128 x 512, k=j) x W^T (512 x 512; B[n=i][k=j], rows k-contiguous!)
// out[b,l] = sum_i Z[l,i] * t1[b,l,i]
//
// BI=128, 512 threads, grid 1024 = 2 blocks/CU x 256 CU x 2 rounds.
// 8 waves = 4(wv: l-rows) x 2(ih: i-halves of the 128-col tile); per-wave
// acc[2][4] (32 AGPR). Double-buffered LDS (2 x 36 KB), ONE barrier per
// k-iteration: cvt+ds_writes of tile k+1 overlap the MFMA clusters of
// tile k (different LDS buffer -> no WAR), loads for k+2 issue-pinned
// with sched_barrier. setprio(1) around MFMA (stage/MFMA role-split).
//
// Placement: XCD x = g&7 owns expert-sorted batch slots x*32..x*32+31;
// per-XCD sequence interleaves it=0..3 of each b so all 4 i-tiles of a
// batch are co-resident -> t2 + weight L2 reuse.
template <bool USE_PERM>
__global__ __launch_bounds__(512, 4) void pdot_kernel(
    const float* __restrict__ t1, const float* __restrict__ t2,
    const int* __restrict__ pidx, const float* __restrict__ wgt,
    const int* __restrict__ perm, float* __restrict__ out)
{
    __shared__ unsigned short sm[2][BUFSZ];   // [buf][ sA(128 rows) | sB(128 rows) ]

    const int g  = blockIdx.x;
    const int x  = g & 7;                 // XCD
    const int s  = g >> 3;                // per-XCD sequence 0..127
    const int slot = x * 32 + (s >> 2);   // expert-sorted batch slot
    const int b  = USE_PERM ? perm[slot] : slot;
    const int it = s & 3;
    const int i0 = it * BI;

    const int t  = threadIdx.x;
    const int w  = t >> 6;         // wave 0..7
    const int wv = w & 3;          // l-group: rows wv*32..wv*32+31
    const int ih = w >> 2;         // i-half: cols ih*64..ih*64+63 of the tile
    const int ln = t & 63;
    const int nh = ln & 15;
    const int qd = ln >> 4;

    const int e = pidx[b];
    const float* aPtr = t2  + (size_t)b * (NL * ND2);
    const float* bPtr = wgt + (size_t)e * (ND1 * ND2) + (size_t)i0 * ND2;
    const float* t1p  = t1  + (size_t)b * (NL * ND1) + i0 + ih * 64;

    float4_t acc[2][4];
    #pragma unroll
    for (int i = 0; i < 2; ++i)
        #pragma unroll
        for (int j = 0; j < 4; ++j) {
            float4_t z = {0.f, 0.f, 0.f, 0.f};
            acc[i][j] = z;
        }

    // staging map: A tile 128x64 fp32 = 2048 float4; 512 threads -> 4 each.
    // pass p covers rows p*32..p*32+31; lane (t&15) owns one 16B chunk.
    const int s_row = t >> 4;          // 0..31, +p*32
    const int s_kq  = (t & 15) * 4;
    const size_t sOff = (size_t)s_row * ND2 + s_kq;
    const int wOff  = s_row * LDST + s_kq;           // ushort offset within sA
    const int wOffB = (NL + s_row) * LDST + s_kq;    // within sB

    float4_t pa[4], pb[4];   // in-flight prefetch (32 VGPRs)

    // ---- prologue: load+stage tile 0 into buf0; issue loads of tile 1 ----
    #pragma unroll
    for (int p = 0; p < 4; ++p) {
        pa[p] = *(const float4_t*)(aPtr + sOff + (size_t)p * (32 * ND2));
        pb[p] = *(const float4_t*)(bPtr + sOff + (size_t)p * (32 * ND2));
    }
    #pragma unroll
    for (int p = 0; p < 4; ++p) {
        *(ushort4_t*)(&sm[0][wOff  + p * (32 * LDST)]) = cvt4(pa[p]);
        *(ushort4_t*)(&sm[0][wOffB + p * (32 * LDST)]) = cvt4(pb[p]);
    }
    #pragma unroll
    for (int p = 0; p < 4; ++p) {
        pa[p] = *(const float4_t*)(aPtr + sOff + BK + (size_t)p * (32 * ND2));
        pb[p] = *(const float4_t*)(bPtr + sOff + BK + (size_t)p * (32 * ND2));
    }
    __builtin_amdgcn_sched_barrier(0);
    asm volatile("s_waitcnt lgkmcnt(0)" ::: "memory");
    __builtin_amdgcn_sched_barrier(0);
    __builtin_amdgcn_s_barrier();
    __builtin_amdgcn_sched_barrier(0);

    #pragma unroll
    for (int kt = 0; kt < NKT; ++kt) {
        const int cur = kt & 1;
        const int nxt = cur ^ 1;
        const unsigned short* cA = &sm[cur][0];
        const unsigned short* cB = &sm[cur][NL * LDST];

        // ---- ks=0: compute (buf cur) ----
        {
            const int kf = qd * 8;
            const int ra = wv * 32 + nh;
            bf16x8_t af0 = __builtin_bit_cast(bf16x8_t, *(const ushort8_t*)(&cA[(ra     ) * LDST + kf]));
            bf16x8_t af1 = __builtin_bit_cast(bf16x8_t, *(const ushort8_t*)(&cA[(ra + 16) * LDST + kf]));
            bf16x8_t bv[4];
            #pragma unroll
            for (int ns = 0; ns < 4; ++ns)
                bv[ns] = __builtin_bit_cast(bf16x8_t, *(const ushort8_t*)(&cB[(ih * 64 + ns * 16 + nh) * LDST + kf]));
            __builtin_amdgcn_s_setprio(1);
            #pragma unroll
            for (int ns = 0; ns < 4; ++ns) {
                acc[0][ns] = __builtin_amdgcn_mfma_f32_16x16x32_bf16(af0, bv[ns], acc[0][ns], 0, 0, 0);
                acc[1][ns] = __builtin_amdgcn_mfma_f32_16x16x32_bf16(af1, bv[ns], acc[1][ns], 0, 0, 0);
            }
            __builtin_amdgcn_s_setprio(0);
        }

        // ---- overlapped stage, half 1: A-tile of kt+1 into buf nxt ----
        if (kt < NKT - 1) {
            #pragma unroll
            for (int p = 0; p < 4; ++p)
                *(ushort4_t*)(&sm[nxt][wOff + p * (32 * LDST)]) = cvt4(pa[p]);
        }

        // ---- ks=1: compute (buf cur) ----
        {
            const int kf = 32 + qd * 8;
            const int ra = wv * 32 + nh;
            bf16x8_t af0 = __builtin_bit_cast(bf16x8_t, *(const ushort8_t*)(&cA[(ra     ) * LDST + kf]));
            bf16x8_t af1 = __builtin_bit_cast(bf16x8_t, *(const ushort8_t*)(&cA[(ra + 16) * LDST + kf]));
            bf16x8_t bv[4];
            #pragma unroll
            for (int ns = 0; ns < 4; ++ns)
                bv[ns] = __builtin_bit_cast(bf16x8_t, *(const ushort8_t*)(&cB[(ih * 64 + ns * 16 + nh) * LDST + kf]));
            __builtin_amdgcn_s_setprio(1);
            #pragma unroll
            for (int ns = 0; ns < 4; ++ns) {
                acc[0][ns] = __builtin_amdgcn_mfma_f32_16x16x32_bf16(af0, bv[ns], acc[0][ns], 0, 0, 0);
                acc[1][ns] = __builtin_amdgcn_mfma_f32_16x16x32_bf16(af1, bv[ns], acc[1][ns], 0, 0, 0);
            }
            __builtin_amdgcn_s_setprio(0);
        }

        if (kt < NKT - 1) {
            // ---- overlapped stage, half 2: B-tile of kt+1 into buf nxt ----
            #pragma unroll
            for (int p = 0; p < 4; ++p)
                *(ushort4_t*)(&sm[nxt][wOffB + p * (32 * LDST)]) = cvt4(pb[p]);
            // ---- issue loads for tile kt+2 (pinned: cannot sink below) ----
            if (kt < NKT - 2) {
                const size_t k0 = (size_t)(kt + 2) * BK;
                #pragma unroll
                for (int p = 0; p < 4; ++p) {
                    pa[p] = *(const float4_t*)(aPtr + sOff + k0 + (size_t)p * (32 * ND2));
                    pb[p] = *(const float4_t*)(bPtr + sOff + k0 + (size_t)p * (32 * ND2));
                }
                __builtin_amdgcn_sched_barrier(0);
            }
            // ---- single barrier per iteration ----
            asm volatile("s_waitcnt lgkmcnt(0)" ::: "memory");  // my reads retired + my writes visible
            __builtin_amdgcn_sched_barrier(0);
            __builtin_amdgcn_s_barrier();
            __builtin_amdgcn_sched_barrier(0);
        }
    }

    // epilogue: out[b,l] += sum over this wave's i-columns of Z[l,i]*t1[l,i]
    // C/D: col(n=i) = ih*64 + ns*16 + nh, row(m=l) = wv*32 + ms*16 + qd*4 + r
    #pragma unroll
    for (int ms = 0; ms < 2; ++ms) {
        #pragma unroll
        for (int r = 0; r < 4; ++r) {
            const int row = wv * 32 + ms * 16 + qd * 4 + r;
            float ps = 0.f;
            #pragma unroll
            for (int ns = 0; ns < 4; ++ns) {
                const float tv = t1p[(size_t)row * ND1 + ns * 16 + nh];
                ps += acc[ms][ns][r] * tv;
            }
            ps += __shfl_xor(ps, 1);
            ps += __shfl_xor(ps, 2);
            ps += __shfl_xor(ps, 4);
            ps += __shfl_xor(ps, 8);
            if (nh == 0) atomicAdd(&out[b * NL + row], ps);
        }
    }
}

extern "C" void kernel_launch(void* const* d_in, const int* in_sizes, int n_in,
                              void* d_out, int out_size, void* d_ws, size_t ws_size,
                              hipStream_t stream)
{
    const float* t1  = (const float*)d_in[0];
    const float* t2  = (const float*)d_in[1];
    const int* pidx  = (const int*)d_in[2];
    const float* wgt = (const float*)d_in[3];
    float* out = (float*)d_out;

    const int zero_blocks = (out_size + 255) / 256;
    const bool have_ws = ws_size >= NB * sizeof(int);
    int* perm = have_ws ? (int*)d_ws : nullptr;

    pre_kernel<<<dim3(zero_blocks), dim3(256), 0, stream>>>(pidx, perm, out, out_size, have_ws ? 1 : 0);

    if (have_ws)
        pdot_kernel<true><<<dim3(NB * (ND1 / BI)), dim3(512), 0, stream>>>(t1, t2, pidx, wgt, perm, out);
    else
        pdot_kernel<false><<<dim3(NB * (ND1 / BI)), dim3(512), 0, stream>>>(t1, t2, pidx, wgt, nullptr, out);
}